// Round 11
// baseline (368.989 us; speedup 1.0000x reference)
//
#include <hip/hip_runtime.h>
#include <hip/hip_bf16.h>

typedef __hip_bfloat16 bf16;
using short8 = __attribute__((ext_vector_type(8))) short;
using f32x4  = __attribute__((ext_vector_type(4))) float;
using f32x2  = __attribute__((ext_vector_type(2))) float;

#ifndef __has_builtin
#define __has_builtin(x) 0
#endif
#if __has_builtin(__builtin_amdgcn_global_load_lds)
#define HAVE_GLL 1
#else
#define HAVE_GLL 0
#endif

__device__ inline void stage16(const short* __restrict__ g, short* l, int lane) {
#if HAVE_GLL
  __builtin_amdgcn_global_load_lds((__attribute__((address_space(1))) void*)g,
                                   (__attribute__((address_space(3))) void*)l,
                                   16, 0, 0);
#else
  *(short8*)(l + lane * 8) = *(const short8*)g;
#endif
}

__device__ inline unsigned pack2bf(float a, float b) {
  bf16 h0 = __float2bfloat16(a), h1 = __float2bfloat16(b);
  return (unsigned)*(unsigned short*)&h0 | ((unsigned)*(unsigned short*)&h1 << 16);
}

// ---------------------------------------------------------------------------
// LDS-staged batched GEMM, tile 128x64, BK=64 (m97 structure). C = alpha*A@B^T
// (+bias). A:[M,K](lda) bf16, B:[N,K](ldb) bf16, C bf16 or fp32.
// CLOSED LEVERS: 128x128 tiles regress at 1-3 blocks/CU (R3/R7); K+V
// shared-A fusion regresses (R10: LDS/VGPR growth + dispatch split).
// ---------------------------------------------------------------------------
__global__ __launch_bounds__(256) void gemm_lds64(
    const bf16* __restrict__ Ag, long a_bs1, long a_bs2, int lda,
    const bf16* __restrict__ Bg, long b_bs1, long b_bs2, int ldb,
    void* __restrict__ Cg, long c_bs1, long c_bs2, int ldc,
    const float* __restrict__ bias, int K, int Z2, float alpha, int cf32)
{
  __shared__ short As[128 * 64];
  __shared__ short Bs[64 * 64];

  int z = blockIdx.z, z1 = z / Z2, z2 = z - z1 * Z2;
  const short* A = (const short*)(Ag + z1 * a_bs1 + z2 * a_bs2);
  const short* B = (const short*)(Bg + z1 * b_bs1 + z2 * b_bs2);

  int tid = threadIdx.x, lane = tid & 63, w = tid >> 6;
  int wm = w & 1, wn = w >> 1;
  int m0 = blockIdx.x * 128, n0 = blockIdx.y * 64;
  int r = lane & 15, q = lane >> 4;

  int srow = lane >> 3, scol = (lane & 7) * 8;
  const short* Asrc = A + (long)(m0 + w * 32 + srow) * lda + scol;
  const short* Bsrc = B + (long)(n0 + w * 16 + srow) * ldb + scol;
  short* Adst = As + (w * 32) * 64;
  short* Bdst = Bs + (w * 16) * 64;

  f32x4 acc[4][2];
  #pragma unroll
  for (int i = 0; i < 4; ++i)
    #pragma unroll
    for (int j = 0; j < 2; ++j) acc[i][j] = (f32x4){0.f, 0.f, 0.f, 0.f};

  for (int kt = 0; kt < K; kt += 64) {
    #pragma unroll
    for (int i = 0; i < 4; ++i)
      stage16(Asrc + (long)i * 8 * lda + kt, Adst + i * 8 * 64, lane);
    #pragma unroll
    for (int i = 0; i < 2; ++i)
      stage16(Bsrc + (long)i * 8 * ldb + kt, Bdst + i * 8 * 64, lane);
    __syncthreads();
    #pragma unroll
    for (int kk = 0; kk < 64; kk += 32) {
      short8 af[4], bfr[2];
      #pragma unroll
      for (int i = 0; i < 4; ++i)
        af[i] = *(const short8*)&As[(wm * 64 + i * 16 + r) * 64 + kk + q * 8];
      #pragma unroll
      for (int j = 0; j < 2; ++j)
        bfr[j] = *(const short8*)&Bs[(wn * 32 + j * 16 + r) * 64 + kk + q * 8];
      #pragma unroll
      for (int i = 0; i < 4; ++i)
        #pragma unroll
        for (int j = 0; j < 2; ++j)
          acc[i][j] = __builtin_amdgcn_mfma_f32_16x16x32_bf16(af[i], bfr[j], acc[i][j], 0, 0, 0);
    }
    __syncthreads();
  }

  long cb = z1 * c_bs1 + z2 * c_bs2;
  #pragma unroll
  for (int j = 0; j < 2; ++j) {
    int col = n0 + wn * 32 + j * 16 + r;
    float bv = bias ? bias[col] : 0.0f;
    #pragma unroll
    for (int i = 0; i < 4; ++i) {
      int row0 = m0 + wm * 64 + i * 16 + q * 4;
      #pragma unroll
      for (int rr = 0; rr < 4; ++rr) {
        float val = acc[i][j][rr] * alpha + bv;
        long idx = cb + (long)(row0 + rr) * ldc + col;
        if (cf32) ((float*)Cg)[idx] = val;
        else ((bf16*)Cg)[idx] = __float2bfloat16(val);
      }
    }
  }
}

// ---------------------------------------------------------------------------
// Fused z-batched QKV projection (R9 config): z=0,1 -> Q,K row-major; z=2 ->
// V written DIRECTLY TRANSPOSED to Vt via pitch-65 LDS bounce. 128x64 tiles.
// ---------------------------------------------------------------------------
struct QKVArgs {
  const bf16* A[3];
  const bf16* Bw[3];
  bf16* C[3];               // C[2] = Vt
  const float* bias[3];
};

__global__ __launch_bounds__(256) void gemm_qkv(QKVArgs args) {
  __shared__ short smem[128 * 64 + 64 * 64];   // As | Bs; reused for V bounce
  short* As = smem;
  short* Bs = smem + 128 * 64;

  int z = blockIdx.z;
  const short* A = (const short*)args.A[z];
  const short* B = (const short*)args.Bw[z];
  bf16* C = args.C[z];
  const float* bias = args.bias[z];

  int tid = threadIdx.x, lane = tid & 63, w = tid >> 6;
  int wm = w & 1, wn = w >> 1;
  int m0 = blockIdx.x * 128, n0 = blockIdx.y * 64;
  int r = lane & 15, q = lane >> 4;

  int srow = lane >> 3, scol = (lane & 7) * 8;
  const short* Asrc = A + (long)(m0 + w * 32 + srow) * 1024 + scol;
  const short* Bsrc = B + (long)(n0 + w * 16 + srow) * 1024 + scol;
  short* Adst = As + (w * 32) * 64;
  short* Bdst = Bs + (w * 16) * 64;

  f32x4 acc[4][2];
  #pragma unroll
  for (int i = 0; i < 4; ++i)
    #pragma unroll
    for (int j = 0; j < 2; ++j) acc[i][j] = (f32x4){0.f, 0.f, 0.f, 0.f};

  for (int kt = 0; kt < 1024; kt += 64) {
    #pragma unroll
    for (int i = 0; i < 4; ++i)
      stage16(Asrc + (long)i * 8 * 1024 + kt, Adst + i * 8 * 64, lane);
    #pragma unroll
    for (int i = 0; i < 2; ++i)
      stage16(Bsrc + (long)i * 8 * 1024 + kt, Bdst + i * 8 * 64, lane);
    __syncthreads();
    #pragma unroll
    for (int kk = 0; kk < 64; kk += 32) {
      short8 af[4], bfr[2];
      #pragma unroll
      for (int i = 0; i < 4; ++i)
        af[i] = *(const short8*)&As[(wm * 64 + i * 16 + r) * 64 + kk + q * 8];
      #pragma unroll
      for (int j = 0; j < 2; ++j)
        bfr[j] = *(const short8*)&Bs[(wn * 32 + j * 16 + r) * 64 + kk + q * 8];
      #pragma unroll
      for (int i = 0; i < 4; ++i)
        #pragma unroll
        for (int j = 0; j < 2; ++j)
          acc[i][j] = __builtin_amdgcn_mfma_f32_16x16x32_bf16(af[i], bfr[j], acc[i][j], 0, 0, 0);
    }
    __syncthreads();
  }

  if (z < 2) {
    #pragma unroll
    for (int j = 0; j < 2; ++j) {
      int col = n0 + wn * 32 + j * 16 + r;
      float bv = bias[col];
      #pragma unroll
      for (int i = 0; i < 4; ++i) {
        int row0 = m0 + wm * 64 + i * 16 + q * 4;
        #pragma unroll
        for (int rr = 0; rr < 4; ++rr)
          C[(long)(row0 + rr) * 1024 + col] = __float2bfloat16(acc[i][j][rr] + bv);
      }
    }
  } else {
    // V -> Vt: stage tile [128 rows][64 cols] at pitch 65 (bank spread),
    // drain column-wise with contiguous 16B stores along s.
    #pragma unroll
    for (int j = 0; j < 2; ++j) {
      int cloc = wn * 32 + j * 16 + r;
      float bv = bias[n0 + cloc];
      #pragma unroll
      for (int i = 0; i < 4; ++i) {
        int rloc = wm * 64 + i * 16 + q * 4;
        #pragma unroll
        for (int rr = 0; rr < 4; ++rr) {
          bf16 hv = __float2bfloat16(acc[i][j][rr] + bv);
          smem[(rloc + rr) * 65 + cloc] = *(short*)&hv;
        }
      }
    }
    __syncthreads();
    int bb = m0 >> 10, s0 = m0 & 1023;
    int cl = tid >> 2, rs = (tid & 3) * 32;
    short* vt = (short*)C + (long)bb * 1048576 + (long)(n0 + cl) * 1024 + s0 + rs;
    #pragma unroll
    for (int seg = 0; seg < 4; ++seg) {
      short8 v;
      #pragma unroll
      for (int k = 0; k < 8; ++k)
        v[k] = smem[(rs + seg * 8 + k) * 65 + cl];
      *(short8*)(vt + seg * 8) = v;
    }
  }
}

// ---------------------------------------------------------------------------
// Direct (no-LDS compute) K=64 batched GEMM for scores: tile 128x128, wave
// 64x64. C-write bounced through LDS (2 x 64-row phases, pitch 136) so
// stores are 8 fully-coalesced short8/lane (R9; kept, ~neutral-positive).
// ---------------------------------------------------------------------------
__global__ __launch_bounds__(256) void gemm_k64(
    const bf16* __restrict__ Ag, long a_bs1, long a_bs2, int lda,
    const bf16* __restrict__ Bg, long b_bs1, long b_bs2, int ldb,
    bf16* __restrict__ Cg, long c_bs1, long c_bs2, int ldc,
    int Z2, float alpha)
{
  __shared__ short ct[64 * 136];        // 17 KiB bounce tile (one 64-row phase)

  int z = blockIdx.z, z1 = z / Z2, z2 = z - z1 * Z2;
  const short* A = (const short*)(Ag + z1 * a_bs1 + z2 * a_bs2);
  const short* B = (const short*)(Bg + z1 * b_bs1 + z2 * b_bs2);
  bf16* C = Cg + z1 * c_bs1 + z2 * c_bs2;

  int tid = threadIdx.x, lane = tid & 63, w = tid >> 6;
  int wm = w & 1, wn = w >> 1;
  int bm = blockIdx.x * 128, bn = blockIdx.y * 128;
  int m0 = bm + wm * 64;
  int n0 = bn + wn * 64;
  int r = lane & 15, q = lane >> 4;

  const short* Ar = A + (long)(m0 + r) * lda + q * 8;
  const short* Br = B + (long)(n0 + r) * ldb + q * 8;

  f32x4 acc[4][4];
  #pragma unroll
  for (int i = 0; i < 4; ++i)
    #pragma unroll
    for (int j = 0; j < 4; ++j) acc[i][j] = (f32x4){0.f, 0.f, 0.f, 0.f};

  #pragma unroll
  for (int kk = 0; kk < 64; kk += 32) {
    short8 af[4], bfr[4];
    #pragma unroll
    for (int i = 0; i < 4; ++i) af[i] = *(const short8*)(Ar + (long)i * 16 * lda + kk);
    #pragma unroll
    for (int j = 0; j < 4; ++j) bfr[j] = *(const short8*)(Br + (long)j * 16 * ldb + kk);
    #pragma unroll
    for (int i = 0; i < 4; ++i)
      #pragma unroll
      for (int j = 0; j < 4; ++j)
        acc[i][j] = __builtin_amdgcn_mfma_f32_16x16x32_bf16(af[i], bfr[j], acc[i][j], 0, 0, 0);
  }

  // two-phase coalesced epilogue: waves wm==ph stage their 64x128 half,
  // all threads drain 16B/lane (one 256B row per 16-lane group).
  int rw16 = tid >> 4, c16 = tid & 15;
  #pragma unroll
  for (int ph = 0; ph < 2; ++ph) {
    if (ph == 1) __syncthreads();       // protect ct before overwrite
    if (wm == ph) {
      #pragma unroll
      for (int j = 0; j < 4; ++j) {
        int cl = wn * 64 + j * 16 + r;
        #pragma unroll
        for (int i = 0; i < 4; ++i) {
          int rl = i * 16 + q * 4;
          #pragma unroll
          for (int rr = 0; rr < 4; ++rr) {
            bf16 hv = __float2bfloat16(acc[i][j][rr] * alpha);
            ct[(rl + rr) * 136 + cl] = *(short*)&hv;
          }
        }
      }
    }
    __syncthreads();
    #pragma unroll
    for (int ps = 0; ps < 4; ++ps) {
      int rh = ps * 16 + rw16;
      short8 v = *(const short8*)&ct[rh * 136 + c16 * 8];
      *(short8*)((short*)C + (long)(bm + ph * 64 + rh) * ldc + bn + c16 * 8) = v;
    }
  }
}

// ---------------------------------------------------------------------------
// Merged prologue: z<2 -> fp32->bf16 convert of from/to (4M elems each);
// z=2..5 -> fp32 [1024,1024] -> bf16 transposed weights. One dispatch.
// ---------------------------------------------------------------------------
struct CvtW {
  const float* cf[2]; bf16* co[2];
  const float* ws[4]; bf16* wd[4];
};

__global__ __launch_bounds__(256) void cvtwt(CvtW a) {
  __shared__ bf16 tile[64][66];
  int z = blockIdx.z;
  if (z < 2) {
    const float* in = a.cf[z];
    bf16* out = a.co[z];
    int i = (blockIdx.x * 256 + threadIdx.x) * 8;
    float4 v0 = *(const float4*)(in + i);
    float4 v1 = *(const float4*)(in + i + 4);
    uint4 pk;
    pk.x = pack2bf(v0.x, v0.y);
    pk.y = pack2bf(v0.z, v0.w);
    pk.z = pack2bf(v1.x, v1.y);
    pk.w = pack2bf(v1.z, v1.w);
    *(uint4*)(out + i) = pk;
  } else {
    if (blockIdx.x >= 256) return;
    const float* in = a.ws[z - 2];
    bf16* out = a.wd[z - 2];
    int r0 = (blockIdx.x >> 4) * 64, c0 = (blockIdx.x & 15) * 64;
    int tx = threadIdx.x & 63, ty = threadIdx.x >> 6;
    #pragma unroll
    for (int i = 0; i < 16; ++i) {
      int rr = i * 4 + ty;
      tile[rr][tx] = __float2bfloat16(in[(long)(r0 + rr) * 1024 + c0 + tx]);
    }
    __syncthreads();
    #pragma unroll
    for (int i = 0; i < 16; ++i) {
      int rr = i * 4 + ty;
      out[(long)(c0 + rr) * 1024 + r0 + tx] = tile[tx][rr];
    }
  }
}

// ---------------------------------------------------------------------------
// Talking-heads core v10: v9 structure, but 2 f-rows per block with
// cross-row REGISTER prefetch — row1's chunk-0 score loads + mask loads are
// issued right after row0's last MFMA-consume (register dest, no LDS hazard,
// so they stay in flight across row0's entire reduce+pass2), removing the
// serial block-start load stall for the second row. af1 + weights staging
// amortized over 2 rows. Grid x halves (512).
// ---------------------------------------------------------------------------
__device__ inline void wrows7(short* rowE, short* rowO, const unsigned* ld) {
  union { unsigned u[4]; short8 s; } cv;
  cv.u[0] = (ld[0] & 0xffffu) | (ld[1] << 16);
  cv.u[1] = (ld[2] & 0xffffu) | (ld[3] << 16);
  cv.u[2] = (ld[4] & 0xffffu) | (ld[5] << 16);
  cv.u[3] = (ld[6] & 0xffffu) | (ld[7] << 16);
  *(short8*)rowE = cv.s;                       // even row: 16B-aligned b128
  uint2 d0, d1;
  d0.x = (ld[0] >> 16) | (ld[1] & 0xffff0000u);
  d0.y = (ld[2] >> 16) | (ld[3] & 0xffff0000u);
  d1.x = (ld[4] >> 16) | (ld[5] & 0xffff0000u);
  d1.y = (ld[6] >> 16) | (ld[7] & 0xffff0000u);
  *(uint2*)rowO = d0;                          // odd row: 8B-aligned b64 x2
  *(uint2*)(rowO + 4) = d1;
}

template<int C>
__device__ inline void compute_chunk9(const short* Sb, const float* madds, int tb,
    int g, short8 af1, f32x4& zacc, unsigned (&epk)[8][2]) {
  #pragma unroll
  for (int it = 0; it < 4; ++it) {
    int tl = tb + it * 16;
    const short* rp = Sb + tl * 20 + (g & 1) * 8;
    union { uint2 u2[2]; short8 s; } cv;
    cv.u2[0] = *(const uint2*)rp;
    cv.u2[1] = *(const uint2*)(rp + 4);
    float madd = madds[C * 4 + it];
    f32x4 a = __builtin_amdgcn_mfma_f32_16x16x32_bf16(
        af1, cv.s, (f32x4){madd, madd, madd, madd}, 0, 0, 0);
    f32x4 e;
    #pragma unroll
    for (int j = 0; j < 4; ++j) e[j] = exp2f(a[j]);
    zacc += e;
    epk[C * 4 + it][0] = pack2bf(e[0], e[1]);
    epk[C * 4 + it][1] = pack2bf(e[2], e[3]);
  }
}

template<int C>
__device__ inline void pass2_chunk7(short* Sb, unsigned short* scb, int tb,
    int g, short8 af2, const unsigned (&epk)[8][2],
    const short* rowE, const short* rowO, int nh, int p) {
  // wave-local transpose: E (D-layout regs) -> Sb[t][l'] columns
  #pragma unroll
  for (int it = 0; it < 4; ++it) {
    int tl = tb + it * 16;
    uint2 ev; ev.x = epk[C * 4 + it][0]; ev.y = epk[C * 4 + it][1];
    *(uint2*)(Sb + tl * 20 + g * 4) = ev;
  }
  asm volatile("s_waitcnt lgkmcnt(0)" ::: "memory");
  __builtin_amdgcn_sched_barrier(0);
  #pragma unroll
  for (int it = 0; it < 4; ++it) {
    int tl = tb + it * 16;
    const short* rp = Sb + tl * 20 + (g & 1) * 8;
    union { uint2 u2[2]; short8 s; } cv;
    cv.u2[0] = *(const uint2*)rp;
    cv.u2[1] = *(const uint2*)(rp + 4);
    f32x4 o = __builtin_amdgcn_mfma_f32_16x16x32_bf16(
        af2, cv.s, (f32x4){0.f, 0.f, 0.f, 0.f}, 0, 0, 0);
    uint2 dv; dv.x = pack2bf(o[0], o[1]); dv.y = pack2bf(o[2], o[3]);
    *(uint2*)(Sb + tl * 20 + g * 4) = dv;      // in-place: reads precede (order)
  }
  __syncthreads();
  // coalesced drain: Sb[t][l'] -> global planes, dword stores
  union { unsigned u[4]; short8 s; } de;
  de.s = *(const short8*)rowE;
  uint2 q0 = *(const uint2*)rowO;
  uint2 q1 = *(const uint2*)(rowO + 4);
  unsigned od[4] = {q0.x, q0.y, q1.x, q1.y};
  #pragma unroll
  for (int jj = 0; jj < 4; ++jj) {
    unsigned evw = de.u[jj], odw = od[jj];
    unsigned out0 = (evw & 0xffffu) | (odw << 16);
    unsigned out1 = (evw >> 16) | (odw & 0xffff0000u);
    int n0 = nh * 8 + jj * 2;
    *(unsigned*)(scb + ((long)n0 << 20) + C * 512 + 2 * p) = out0;
    *(unsigned*)(scb + ((long)(n0 + 1) << 20) + C * 512 + 2 * p) = out1;
  }
}

__global__ __launch_bounds__(512, 8) void mixsoftmax10(
    bf16* __restrict__ sc, long sc_bs, const float* __restrict__ pre,
    const float* __restrict__ post, const int* __restrict__ mask)
{
  __shared__ short Sb[512 * 20];        // 20 KiB chunk tile, pitch 20 halves
  __shared__ float wpreS[256], wpostS[256];
  __shared__ float zred[8][16];
  __shared__ float zinvs[16];

  int tid = threadIdx.x;
  int lane = tid & 63, w = tid >> 6;
  int g = lane >> 4, r = lane & 15;
  int b = blockIdx.y;

  unsigned short* scB = (unsigned short*)(sc + (long)b * sc_bs);
  const int* mkB = mask + ((long)b << 20);
  long f0 = blockIdx.x, f1 = blockIdx.x + 512;

  if (tid < 256) {
    wpreS[tid] = pre[tid] * 1.44269504f;   // fold log2(e) into pre-mix
    wpostS[tid] = post[tid];
  }

  // staging role: nh = n-half (0/1), p = t-pair index within chunk
  int nh = tid >> 8, p = tid & 255;
  short* rowE = &Sb[(2 * p) * 20 + nh * 8];
  short* rowO = &Sb[(2 * p + 1) * 20 + nh * 8];
  int tb = w * 64 + r;                  // wave-local col base within chunk

  unsigned short* scb0 = scB + (f0 << 10);
  unsigned short* scb1 = scB + (f1 << 10);
  const unsigned short* sA0 = scb0 + ((long)(nh * 8) << 20) + 2 * p;
  const unsigned short* sA1 = scb1 + ((long)(nh * 8) << 20) + 2 * p;
  const int* mk0 = mkB + (f0 << 10);
  const int* mk1 = mkB + (f1 << 10);

  unsigned epk[8][2];
  unsigned ld[8];
  float madds[8], madds1[8];

  // ---- row0 chunk0 + row0 masks (latency overlapped with weight staging)
  #pragma unroll
  for (int i = 0; i < 8; ++i)
    ld[i] = *(const unsigned*)(sA0 + ((long)i << 20));
  #pragma unroll
  for (int c2 = 0; c2 < 2; ++c2)
    #pragma unroll
    for (int it = 0; it < 4; ++it)
      madds[c2 * 4 + it] =
          (1.0f - (float)mk0[c2 * 512 + tb + it * 16]) * -14426.9504f;
  __syncthreads();                      // wpreS/wpostS ready

  // A1 = wpre^T * log2e (k zero-padded 16->32) — shared by both rows
  short8 af1;
  #pragma unroll
  for (int i = 0; i < 8; ++i) {
    int n = ((g & 1) << 3) + i;
    bf16 hv = __float2bfloat16(wpreS[n * 16 + r]);
    af1[i] = (g < 2) ? *(short*)&hv : (short)0;
  }

  // ======================= row 0 =======================
  f32x4 zacc = (f32x4){0.f, 0.f, 0.f, 0.f};
  wrows7(rowE, rowO, ld);               // stage chunk 0
  __syncthreads();
  #pragma unroll
  for (int i = 0; i < 8; ++i)
    ld[i] = *(const unsigned*)(sA0 + ((long)i << 20) + 512);
  compute_chunk9<0>(Sb, madds, tb, g, af1, zacc, epk);
  __syncthreads();
  wrows7(rowE, rowO, ld);               // stage chunk 1
  __syncthreads();
  compute_chunk9<1>(Sb, madds, tb, g, af1, zacc, epk);

  // prefetch row1 chunk0 + masks into REGISTERS (no LDS hazard; in flight
  // across row0's reduce + both pass2 phases)
  #pragma unroll
  for (int i = 0; i < 8; ++i)
    ld[i] = *(const unsigned*)(sA1 + ((long)i << 20));
  #pragma unroll
  for (int c2 = 0; c2 < 2; ++c2)
    #pragma unroll
    for (int it = 0; it < 4; ++it)
      madds1[c2 * 4 + it] =
          (1.0f - (float)mk1[c2 * 512 + tb + it * 16]) * -14426.9504f;

  #pragma unroll
  for (int m2 = 1; m2 < 16; m2 <<= 1) {
    #pragma unroll
    for (int j = 0; j < 4; ++j) zacc[j] += __shfl_xor(zacc[j], m2, 64);
  }
  if (r == 0) *(f32x4*)&zred[w][g * 4] = zacc;
  __syncthreads();
  if (tid < 64) {                       // one-wave parallel zinv
    int l2 = tid & 15, h = tid >> 4;
    float zsum = zred[h][l2] + zred[h + 4][l2];
    zsum += __shfl_xor(zsum, 16, 64);
    zsum += __shfl_xor(zsum, 32, 64);
    if (tid < 16) zinvs[tid] = 1.0f / zsum;
  }
  __syncthreads();
  short8 af2;
  #pragma unroll
  for (int i = 0; i < 8; ++i) {
    int n = ((g & 1) << 3) + i;
    bf16 hv = __float2bfloat16(wpostS[n * 16 + r] * zinvs[n]);
    af2[i] = (g < 2) ? *(short*)&hv : (short)0;
  }
  pass2_chunk7<0>(Sb, scb0, tb, g, af2, epk, rowE, rowO, nh, p);
  __syncthreads();
  pass2_chunk7<1>(Sb, scb0, tb, g, af2, epk, rowE, rowO, nh, p);
  __syncthreads();                      // protect Sb before row1 staging

  // ======================= row 1 =======================
  zacc = (f32x4){0.f, 0.f, 0.f, 0.f};
  wrows7(rowE, rowO, ld);               // stage chunk 0 (prefetched)
  __syncthreads();
  #pragma unroll
  for (int i = 0; i < 8; ++i)
    ld[i] = *(const unsigned*)(sA1 + ((long)i << 20) + 512);
  compute_chunk9<0>(Sb, madds1, tb, g, af1, zacc, epk);
  __syncthreads();
  wrows7(rowE, rowO, ld);               // stage chunk 1
  __syncthreads();
  compute_chunk9<1>(Sb, madds1, tb, g, af1, zacc, epk);

  #pragma unroll
  for (int m2 = 1; m2 < 16; m2 <<= 1) {
    #pragma unroll
    for (int j = 0; j < 4; ++j) zacc[j] += __shfl_xor(zacc[j], m2, 64);
  }
  if (r == 0) *(f32x4*)&zred[w][g * 4] = zacc;
  __syncthreads();
  if (tid < 64) {
    int l2 = tid & 15, h = tid >> 4;
    float zsum = zred[h][l2] + zred[h + 4][l2];
    zsum += __shfl_xor(zsum, 16, 64);
    zsum += __shfl_xor(zsum, 32, 64);
    if (tid < 16) zinvs[tid] = 1.0f / zsum;
  }
  __syncthreads();
  short8 af2b;
  #pragma unroll
  for (int i = 0; i < 8; ++i) {
    int n = ((g & 1) << 3) + i;
    bf16 hv = __float2bfloat16(wpostS[n * 16 + r] * zinvs[n]);
    af2b[i] = (g < 2) ? *(short*)&hv : (short)0;
  }
  pass2_chunk7<0>(Sb, scb1, tb, g, af2b, epk, rowE, rowO, nh, p);
  __syncthreads();
  pass2_chunk7<1>(Sb, scb1, tb, g, af2b, epk, rowE, rowO, nh, p);
}

// ---------------------------------------------------------------------------
// B=4, S=1024, D=1024, N=16, H=64. fp32 I/O, bf16 internal.
// ws (bf16 elems, M1=1<<20): big path 85M = 170 MB (Sc 64M overlapping the
// dead phase-1 staging), small path 37M = 74 MB (per-batch Sc 16M).
// ---------------------------------------------------------------------------
extern "C" void kernel_launch(void* const* d_in, const int* in_sizes, int n_in,
                              void* d_out, int out_size, void* d_ws, size_t ws_size,
                              hipStream_t stream) {
  const float* from = (const float*)d_in[0];
  const float* to   = (const float*)d_in[1];
  const int*  mask  = (const int*)d_in[2];
  const float* wq = (const float*)d_in[3];
  const float* bq = (const float*)d_in[4];
  const float* wk = (const float*)d_in[5];
  const float* bk = (const float*)d_in[6];
  const float* wv = (const float*)d_in[7];
  const float* bv = (const float*)d_in[8];
  const float* pre  = (const float*)d_in[9];
  const float* post = (const float*)d_in[10];
  const float* wo = (const float*)d_in[11];
  const float* bo = (const float*)d_in[12];
  float* out = (float*)d_out;

  bf16* W = (bf16*)d_ws;
  const long M1 = 1048576;
  bool big = ws_size >= (size_t)(85 * M1) * 2;

  bf16 *Sc, *fromB, *toB, *wqT, *wkT, *wvT, *woT, *Q, *Kp, *Vt, *ctx;
  if (big) {
    Sc = W;                 fromB = W;            toB = W + 4 * M1;
    wqT = W + 8 * M1;       wkT = W + 9 * M1;     wvT = W + 10 * M1;
    woT = W + 64 * M1;      Q = W + 65 * M1;      Kp = W + 69 * M1;
    Vt = W + 77 * M1;       ctx = W + 81 * M1;
  } else {
    Sc = W;                 fromB = W;            toB = W + 4 * M1;
    wqT = W + 8 * M1;       wkT = W + 9 * M1;     wvT = W + 10 * M1;
    woT = W + 16 * M1;      Q = W + 17 * M1;      Kp = W + 21 * M1;
    Vt = W + 29 * M1;       ctx = W + 33 * M1;
  }

  dim3 blk(256);

  // 1) merged converts + weight transposes (single dispatch)
  CvtW cw;
  cw.cf[0] = from; cw.cf[1] = to;
  cw.co[0] = fromB; cw.co[1] = toB;
  cw.ws[0] = wq; cw.ws[1] = wk; cw.ws[2] = wv; cw.ws[3] = wo;
  cw.wd[0] = wqT; cw.wd[1] = wkT; cw.wd[2] = wvT; cw.wd[3] = woT;
  cvtwt<<<dim3(2048, 1, 6), blk, 0, stream>>>(cw);

  // 2) QKV projections (1 z-batched dispatch, R9 config); z=2 writes Vt
  QKVArgs qa;
  qa.A[0] = fromB; qa.A[1] = toB; qa.A[2] = toB;
  qa.Bw[0] = wqT;  qa.Bw[1] = wkT; qa.Bw[2] = wvT;
  qa.C[0] = Q;     qa.C[1] = Kp;  qa.C[2] = Vt;
  qa.bias[0] = bq; qa.bias[1] = bk; qa.bias[2] = bv;
  gemm_qkv<<<dim3(32, 16, 3), blk, 0, stream>>>(qa);

  if (big) {
    // 3) scores (direct K=64): z=(b,n): Sc[b,n] = 0.125*Q[b,:,n,:]@K[b,:,n,:]^T
    gemm_k64<<<dim3(8, 8, 64), blk, 0, stream>>>(
        Q, M1, 64, 1024, Kp, M1, 64, 1024, Sc, 16 * M1, M1, 1024, 16, 0.125f);
    // 4) talking-heads softmax (v10: 2 rows/block, cross-row prefetch)
    mixsoftmax10<<<dim3(512, 4), dim3(512), 0, stream>>>(Sc, 16 * M1, pre, post, mask);
    // 5) PV: z=(b,l): ctx[b,:,l,:] = Sc[b,l]@Vt[b,l]^T
    gemm_lds64<<<dim3(8, 1, 64), blk, 0, stream>>>(
        Sc, 16 * M1, M1, 1024, Vt, M1, 65536, 1024, ctx, M1, 64, 1024, nullptr,
        1024, 16, 1.0f, 0);
  } else {
    for (int b = 0; b < 4; ++b) {
      gemm_k64<<<dim3(8, 8, 16), blk, 0, stream>>>(
          Q + b * M1, 0, 64, 1024, Kp + b * M1, 0, 64, 1024,
          Sc, 0, M1, 1024, 16, 0.125f);
      mixsoftmax10<<<dim3(512, 1), dim3(512), 0, stream>>>(Sc, 0, pre, post, mask + b * M1);
      gemm_lds64<<<dim3(8, 1, 16), blk, 0, stream>>>(
          Sc, 0, M1, 1024, Vt + b * M1, 0, 65536, 1024,
          ctx + b * M1, 0, 64, 1024, nullptr, 1024, 16, 1.0f, 0);
    }
  }

  // 6) out = ctx [4096,1024] @ woT^T + bo -> d_out (fp32), 128x64 tiles
  gemm_lds64<<<dim3(32, 16, 1), blk, 0, stream>>>(
      ctx, 0, 0, 1024, woT, 0, 0, 1024, out, 0, 0, 1024, bo, 1024, 1, 1.0f, 1);
}

// Round 12
// 324.312 us; speedup vs baseline: 1.1378x; 1.1378x over previous
//
#include <hip/hip_runtime.h>
#include <hip/hip_bf16.h>

typedef __hip_bfloat16 bf16;
using short8 = __attribute__((ext_vector_type(8))) short;
using f32x4  = __attribute__((ext_vector_type(4))) float;
using f32x2  = __attribute__((ext_vector_type(2))) float;

#ifndef __has_builtin
#define __has_builtin(x) 0
#endif
#if __has_builtin(__builtin_amdgcn_global_load_lds)
#define HAVE_GLL 1
#else
#define HAVE_GLL 0
#endif

__device__ inline void stage16(const short* __restrict__ g, short* l, int lane) {
#if HAVE_GLL
  __builtin_amdgcn_global_load_lds((__attribute__((address_space(1))) void*)g,
                                   (__attribute__((address_space(3))) void*)l,
                                   16, 0, 0);
#else
  *(short8*)(l + lane * 8) = *(const short8*)g;
#endif
}

__device__ inline unsigned pack2bf(float a, float b) {
  bf16 h0 = __float2bfloat16(a), h1 = __float2bfloat16(b);
  return (unsigned)*(unsigned short*)&h0 | ((unsigned)*(unsigned short*)&h1 << 16);
}

// ---------------------------------------------------------------------------
// LDS-staged batched GEMM, tile 128x64, BK=64 (m97 structure). C = alpha*A@B^T
// (+bias). A:[M,K](lda) bf16, B:[N,K](ldb) bf16, C bf16 or fp32.
// CLOSED LEVERS (A/B'd): 128x128 tiles regress at 1-3 blocks/CU (R3/R7);
// K+V shared-A fusion regresses (R10); multi-row blocks double L3 footprint
// and flip L3-absorbed kernels to HBM-bound (R11).
// ---------------------------------------------------------------------------
__global__ __launch_bounds__(256) void gemm_lds64(
    const bf16* __restrict__ Ag, long a_bs1, long a_bs2, int lda,
    const bf16* __restrict__ Bg, long b_bs1, long b_bs2, int ldb,
    void* __restrict__ Cg, long c_bs1, long c_bs2, int ldc,
    const float* __restrict__ bias, int K, int Z2, float alpha, int cf32)
{
  __shared__ short As[128 * 64];
  __shared__ short Bs[64 * 64];

  int z = blockIdx.z, z1 = z / Z2, z2 = z - z1 * Z2;
  const short* A = (const short*)(Ag + z1 * a_bs1 + z2 * a_bs2);
  const short* B = (const short*)(Bg + z1 * b_bs1 + z2 * b_bs2);

  int tid = threadIdx.x, lane = tid & 63, w = tid >> 6;
  int wm = w & 1, wn = w >> 1;
  int m0 = blockIdx.x * 128, n0 = blockIdx.y * 64;
  int r = lane & 15, q = lane >> 4;

  int srow = lane >> 3, scol = (lane & 7) * 8;
  const short* Asrc = A + (long)(m0 + w * 32 + srow) * lda + scol;
  const short* Bsrc = B + (long)(n0 + w * 16 + srow) * ldb + scol;
  short* Adst = As + (w * 32) * 64;
  short* Bdst = Bs + (w * 16) * 64;

  f32x4 acc[4][2];
  #pragma unroll
  for (int i = 0; i < 4; ++i)
    #pragma unroll
    for (int j = 0; j < 2; ++j) acc[i][j] = (f32x4){0.f, 0.f, 0.f, 0.f};

  for (int kt = 0; kt < K; kt += 64) {
    #pragma unroll
    for (int i = 0; i < 4; ++i)
      stage16(Asrc + (long)i * 8 * lda + kt, Adst + i * 8 * 64, lane);
    #pragma unroll
    for (int i = 0; i < 2; ++i)
      stage16(Bsrc + (long)i * 8 * ldb + kt, Bdst + i * 8 * 64, lane);
    __syncthreads();
    #pragma unroll
    for (int kk = 0; kk < 64; kk += 32) {
      short8 af[4], bfr[2];
      #pragma unroll
      for (int i = 0; i < 4; ++i)
        af[i] = *(const short8*)&As[(wm * 64 + i * 16 + r) * 64 + kk + q * 8];
      #pragma unroll
      for (int j = 0; j < 2; ++j)
        bfr[j] = *(const short8*)&Bs[(wn * 32 + j * 16 + r) * 64 + kk + q * 8];
      #pragma unroll
      for (int i = 0; i < 4; ++i)
        #pragma unroll
        for (int j = 0; j < 2; ++j)
          acc[i][j] = __builtin_amdgcn_mfma_f32_16x16x32_bf16(af[i], bfr[j], acc[i][j], 0, 0, 0);
    }
    __syncthreads();
  }

  long cb = z1 * c_bs1 + z2 * c_bs2;
  #pragma unroll
  for (int j = 0; j < 2; ++j) {
    int col = n0 + wn * 32 + j * 16 + r;
    float bv = bias ? bias[col] : 0.0f;
    #pragma unroll
    for (int i = 0; i < 4; ++i) {
      int row0 = m0 + wm * 64 + i * 16 + q * 4;
      #pragma unroll
      for (int rr = 0; rr < 4; ++rr) {
        float val = acc[i][j][rr] * alpha + bv;
        long idx = cb + (long)(row0 + rr) * ldc + col;
        if (cf32) ((float*)Cg)[idx] = val;
        else ((bf16*)Cg)[idx] = __float2bfloat16(val);
      }
    }
  }
}

// ---------------------------------------------------------------------------
// Fused z-batched QKV projection (R9 config): z=0,1 -> Q,K row-major; z=2 ->
// V written DIRECTLY TRANSPOSED to Vt via pitch-65 LDS bounce. 128x64 tiles.
// ---------------------------------------------------------------------------
struct QKVArgs {
  const bf16* A[3];
  const bf16* Bw[3];
  bf16* C[3];               // C[2] = Vt
  const float* bias[3];
};

__global__ __launch_bounds__(256) void gemm_qkv(QKVArgs args) {
  __shared__ short smem[128 * 64 + 64 * 64];   // As | Bs; reused for V bounce
  short* As = smem;
  short* Bs = smem + 128 * 64;

  int z = blockIdx.z;
  const short* A = (const short*)args.A[z];
  const short* B = (const short*)args.Bw[z];
  bf16* C = args.C[z];
  const float* bias = args.bias[z];

  int tid = threadIdx.x, lane = tid & 63, w = tid >> 6;
  int wm = w & 1, wn = w >> 1;
  int m0 = blockIdx.x * 128, n0 = blockIdx.y * 64;
  int r = lane & 15, q = lane >> 4;

  int srow = lane >> 3, scol = (lane & 7) * 8;
  const short* Asrc = A + (long)(m0 + w * 32 + srow) * 1024 + scol;
  const short* Bsrc = B + (long)(n0 + w * 16 + srow) * 1024 + scol;
  short* Adst = As + (w * 32) * 64;
  short* Bdst = Bs + (w * 16) * 64;

  f32x4 acc[4][2];
  #pragma unroll
  for (int i = 0; i < 4; ++i)
    #pragma unroll
    for (int j = 0; j < 2; ++j) acc[i][j] = (f32x4){0.f, 0.f, 0.f, 0.f};

  for (int kt = 0; kt < 1024; kt += 64) {
    #pragma unroll
    for (int i = 0; i < 4; ++i)
      stage16(Asrc + (long)i * 8 * 1024 + kt, Adst + i * 8 * 64, lane);
    #pragma unroll
    for (int i = 0; i < 2; ++i)
      stage16(Bsrc + (long)i * 8 * 1024 + kt, Bdst + i * 8 * 64, lane);
    __syncthreads();
    #pragma unroll
    for (int kk = 0; kk < 64; kk += 32) {
      short8 af[4], bfr[2];
      #pragma unroll
      for (int i = 0; i < 4; ++i)
        af[i] = *(const short8*)&As[(wm * 64 + i * 16 + r) * 64 + kk + q * 8];
      #pragma unroll
      for (int j = 0; j < 2; ++j)
        bfr[j] = *(const short8*)&Bs[(wn * 32 + j * 16 + r) * 64 + kk + q * 8];
      #pragma unroll
      for (int i = 0; i < 4; ++i)
        #pragma unroll
        for (int j = 0; j < 2; ++j)
          acc[i][j] = __builtin_amdgcn_mfma_f32_16x16x32_bf16(af[i], bfr[j], acc[i][j], 0, 0, 0);
    }
    __syncthreads();
  }

  if (z < 2) {
    #pragma unroll
    for (int j = 0; j < 2; ++j) {
      int col = n0 + wn * 32 + j * 16 + r;
      float bv = bias[col];
      #pragma unroll
      for (int i = 0; i < 4; ++i) {
        int row0 = m0 + wm * 64 + i * 16 + q * 4;
        #pragma unroll
        for (int rr = 0; rr < 4; ++rr)
          C[(long)(row0 + rr) * 1024 + col] = __float2bfloat16(acc[i][j][rr] + bv);
      }
    }
  } else {
    // V -> Vt: stage tile [128 rows][64 cols] at pitch 65 (bank spread),
    // drain column-wise with contiguous 16B stores along s.
    #pragma unroll
    for (int j = 0; j < 2; ++j) {
      int cloc = wn * 32 + j * 16 + r;
      float bv = bias[n0 + cloc];
      #pragma unroll
      for (int i = 0; i < 4; ++i) {
        int rloc = wm * 64 + i * 16 + q * 4;
        #pragma unroll
        for (int rr = 0; rr < 4; ++rr) {
          bf16 hv = __float2bfloat16(acc[i][j][rr] + bv);
          smem[(rloc + rr) * 65 + cloc] = *(short*)&hv;
        }
      }
    }
    __syncthreads();
    int bb = m0 >> 10, s0 = m0 & 1023;
    int cl = tid >> 2, rs = (tid & 3) * 32;
    short* vt = (short*)C + (long)bb * 1048576 + (long)(n0 + cl) * 1024 + s0 + rs;
    #pragma unroll
    for (int seg = 0; seg < 4; ++seg) {
      short8 v;
      #pragma unroll
      for (int k = 0; k < 8; ++k)
        v[k] = smem[(rs + seg * 8 + k) * 65 + cl];
      *(short8*)(vt + seg * 8) = v;
    }
  }
}

// ---------------------------------------------------------------------------
// Direct (no-LDS compute) K=64 batched GEMM for scores: tile 128x128, wave
// 64x64. C-write bounced through LDS (2 x 64-row phases, pitch 136) so
// stores are 8 fully-coalesced short8/lane (R9; kept, ~neutral-positive).
// ---------------------------------------------------------------------------
__global__ __launch_bounds__(256) void gemm_k64(
    const bf16* __restrict__ Ag, long a_bs1, long a_bs2, int lda,
    const bf16* __restrict__ Bg, long b_bs1, long b_bs2, int ldb,
    bf16* __restrict__ Cg, long c_bs1, long c_bs2, int ldc,
    int Z2, float alpha)
{
  __shared__ short ct[64 * 136];        // 17 KiB bounce tile (one 64-row phase)

  int z = blockIdx.z, z1 = z / Z2, z2 = z - z1 * Z2;
  const short* A = (const short*)(Ag + z1 * a_bs1 + z2 * a_bs2);
  const short* B = (const short*)(Bg + z1 * b_bs1 + z2 * b_bs2);
  bf16* C = Cg + z1 * c_bs1 + z2 * c_bs2;

  int tid = threadIdx.x, lane = tid & 63, w = tid >> 6;
  int wm = w & 1, wn = w >> 1;
  int bm = blockIdx.x * 128, bn = blockIdx.y * 128;
  int m0 = bm + wm * 64;
  int n0 = bn + wn * 64;
  int r = lane & 15, q = lane >> 4;

  const short* Ar = A + (long)(m0 + r) * lda + q * 8;
  const short* Br = B + (long)(n0 + r) * ldb + q * 8;

  f32x4 acc[4][4];
  #pragma unroll
  for (int i = 0; i < 4; ++i)
    #pragma unroll
    for (int j = 0; j < 4; ++j) acc[i][j] = (f32x4){0.f, 0.f, 0.f, 0.f};

  #pragma unroll
  for (int kk = 0; kk < 64; kk += 32) {
    short8 af[4], bfr[4];
    #pragma unroll
    for (int i = 0; i < 4; ++i) af[i] = *(const short8*)(Ar + (long)i * 16 * lda + kk);
    #pragma unroll
    for (int j = 0; j < 4; ++j) bfr[j] = *(const short8*)(Br + (long)j * 16 * ldb + kk);
    #pragma unroll
    for (int i = 0; i < 4; ++i)
      #pragma unroll
      for (int j = 0; j < 4; ++j)
        acc[i][j] = __builtin_amdgcn_mfma_f32_16x16x32_bf16(af[i], bfr[j], acc[i][j], 0, 0, 0);
  }

  // two-phase coalesced epilogue: waves wm==ph stage their 64x128 half,
  // all threads drain 16B/lane (one 256B row per 16-lane group).
  int rw16 = tid >> 4, c16 = tid & 15;
  #pragma unroll
  for (int ph = 0; ph < 2; ++ph) {
    if (ph == 1) __syncthreads();       // protect ct before overwrite
    if (wm == ph) {
      #pragma unroll
      for (int j = 0; j < 4; ++j) {
        int cl = wn * 64 + j * 16 + r;
        #pragma unroll
        for (int i = 0; i < 4; ++i) {
          int rl = i * 16 + q * 4;
          #pragma unroll
          for (int rr = 0; rr < 4; ++rr) {
            bf16 hv = __float2bfloat16(acc[i][j][rr] * alpha);
            ct[(rl + rr) * 136 + cl] = *(short*)&hv;
          }
        }
      }
    }
    __syncthreads();
    #pragma unroll
    for (int ps = 0; ps < 4; ++ps) {
      int rh = ps * 16 + rw16;
      short8 v = *(const short8*)&ct[rh * 136 + c16 * 8];
      *(short8*)((short*)C + (long)(bm + ph * 64 + rh) * ldc + bn + c16 * 8) = v;
    }
  }
}

// ---------------------------------------------------------------------------
// Merged prologue: z<2 -> fp32->bf16 convert of from/to (4M elems each);
// z=2..5 -> fp32 [1024,1024] -> bf16 transposed weights. One dispatch.
// ---------------------------------------------------------------------------
struct CvtW {
  const float* cf[2]; bf16* co[2];
  const float* ws[4]; bf16* wd[4];
};

__global__ __launch_bounds__(256) void cvtwt(CvtW a) {
  __shared__ bf16 tile[64][66];
  int z = blockIdx.z;
  if (z < 2) {
    const float* in = a.cf[z];
    bf16* out = a.co[z];
    int i = (blockIdx.x * 256 + threadIdx.x) * 8;
    float4 v0 = *(const float4*)(in + i);
    float4 v1 = *(const float4*)(in + i + 4);
    uint4 pk;
    pk.x = pack2bf(v0.x, v0.y);
    pk.y = pack2bf(v0.z, v0.w);
    pk.z = pack2bf(v1.x, v1.y);
    pk.w = pack2bf(v1.z, v1.w);
    *(uint4*)(out + i) = pk;
  } else {
    if (blockIdx.x >= 256) return;
    const float* in = a.ws[z - 2];
    bf16* out = a.wd[z - 2];
    int r0 = (blockIdx.x >> 4) * 64, c0 = (blockIdx.x & 15) * 64;
    int tx = threadIdx.x & 63, ty = threadIdx.x >> 6;
    #pragma unroll
    for (int i = 0; i < 16; ++i) {
      int rr = i * 4 + ty;
      tile[rr][tx] = __float2bfloat16(in[(long)(r0 + rr) * 1024 + c0 + tx]);
    }
    __syncthreads();
    #pragma unroll
    for (int i = 0; i < 16; ++i) {
      int rr = i * 4 + ty;
      out[(long)(c0 + rr) * 1024 + r0 + tx] = tile[tx][rr];
    }
  }
}

// ---------------------------------------------------------------------------
// Talking-heads core v9 (R9 exact config — best measured). 1 f-row per block:
// R11 proved 2 rows/block doubles the simultaneous L3 footprint, breaking
// the Infinity-Cache absorption (FETCH 74->147 MB, 65->107 us). Latency-bound
// at 4 blocks/CU, no pipe >50% — plateaued across v7/v8/v9 variants.
// ---------------------------------------------------------------------------
__device__ inline void wrows7(short* rowE, short* rowO, const unsigned* ld) {
  union { unsigned u[4]; short8 s; } cv;
  cv.u[0] = (ld[0] & 0xffffu) | (ld[1] << 16);
  cv.u[1] = (ld[2] & 0xffffu) | (ld[3] << 16);
  cv.u[2] = (ld[4] & 0xffffu) | (ld[5] << 16);
  cv.u[3] = (ld[6] & 0xffffu) | (ld[7] << 16);
  *(short8*)rowE = cv.s;                       // even row: 16B-aligned b128
  uint2 d0, d1;
  d0.x = (ld[0] >> 16) | (ld[1] & 0xffff0000u);
  d0.y = (ld[2] >> 16) | (ld[3] & 0xffff0000u);
  d1.x = (ld[4] >> 16) | (ld[5] & 0xffff0000u);
  d1.y = (ld[6] >> 16) | (ld[7] & 0xffff0000u);
  *(uint2*)rowO = d0;                          // odd row: 8B-aligned b64 x2
  *(uint2*)(rowO + 4) = d1;
}

template<int C>
__device__ inline void compute_chunk9(const short* Sb, const float* madds, int tb,
    int g, short8 af1, f32x4& zacc, unsigned (&epk)[8][2]) {
  #pragma unroll
  for (int it = 0; it < 4; ++it) {
    int tl = tb + it * 16;
    const short* rp = Sb + tl * 20 + (g & 1) * 8;
    union { uint2 u2[2]; short8 s; } cv;
    cv.u2[0] = *(const uint2*)rp;
    cv.u2[1] = *(const uint2*)(rp + 4);
    float madd = madds[C * 4 + it];
    f32x4 a = __builtin_amdgcn_mfma_f32_16x16x32_bf16(
        af1, cv.s, (f32x4){madd, madd, madd, madd}, 0, 0, 0);
    f32x4 e;
    #pragma unroll
    for (int j = 0; j < 4; ++j) e[j] = exp2f(a[j]);
    zacc += e;
    epk[C * 4 + it][0] = pack2bf(e[0], e[1]);
    epk[C * 4 + it][1] = pack2bf(e[2], e[3]);
  }
}

template<int C>
__device__ inline void pass2_chunk7(short* Sb, unsigned short* scb, int tb,
    int g, short8 af2, const unsigned (&epk)[8][2],
    const short* rowE, const short* rowO, int nh, int p) {
  // wave-local transpose: E (D-layout regs) -> Sb[t][l'] columns
  #pragma unroll
  for (int it = 0; it < 4; ++it) {
    int tl = tb + it * 16;
    uint2 ev; ev.x = epk[C * 4 + it][0]; ev.y = epk[C * 4 + it][1];
    *(uint2*)(Sb + tl * 20 + g * 4) = ev;
  }
  asm volatile("s_waitcnt lgkmcnt(0)" ::: "memory");
  __builtin_amdgcn_sched_barrier(0);
  #pragma unroll
  for (int it = 0; it < 4; ++it) {
    int tl = tb + it * 16;
    const short* rp = Sb + tl * 20 + (g & 1) * 8;
    union { uint2 u2[2]; short8 s; } cv;
    cv.u2[0] = *(const uint2*)rp;
    cv.u2[1] = *(const uint2*)(rp + 4);
    f32x4 o = __builtin_amdgcn_mfma_f32_16x16x32_bf16(
        af2, cv.s, (f32x4){0.f, 0.f, 0.f, 0.f}, 0, 0, 0);
    uint2 dv; dv.x = pack2bf(o[0], o[1]); dv.y = pack2bf(o[2], o[3]);
    *(uint2*)(Sb + tl * 20 + g * 4) = dv;      // in-place: reads precede (order)
  }
  __syncthreads();
  // coalesced drain: Sb[t][l'] -> global planes, dword stores
  union { unsigned u[4]; short8 s; } de;
  de.s = *(const short8*)rowE;
  uint2 q0 = *(const uint2*)rowO;
  uint2 q1 = *(const uint2*)(rowO + 4);
  unsigned od[4] = {q0.x, q0.y, q1.x, q1.y};
  #pragma unroll
  for (int jj = 0; jj < 4; ++jj) {
    unsigned evw = de.u[jj], odw = od[jj];
    unsigned out0 = (evw & 0xffffu) | (odw << 16);
    unsigned out1 = (evw >> 16) | (odw & 0xffff0000u);
    int n0 = nh * 8 + jj * 2;
    *(unsigned*)(scb + ((long)n0 << 20) + C * 512 + 2 * p) = out0;
    *(unsigned*)(scb + ((long)(n0 + 1) << 20) + C * 512 + 2 * p) = out1;
  }
}

__global__ __launch_bounds__(512, 8) void mixsoftmax9(
    bf16* __restrict__ sc, long sc_bs, const float* __restrict__ pre,
    const float* __restrict__ post, const int* __restrict__ mask)
{
  __shared__ short Sb[512 * 20];        // 20 KiB chunk tile, pitch 20 halves
  __shared__ float wpreS[256], wpostS[256];
  __shared__ float zred[8][16];
  __shared__ float zinvs[16];

  int tid = threadIdx.x;
  int lane = tid & 63, w = tid >> 6;
  int g = lane >> 4, r = lane & 15;
  int f = blockIdx.x, b = blockIdx.y;

  unsigned short* scb = (unsigned short*)(sc + (long)b * sc_bs) + ((long)f << 10);
  const int* mk = mask + ((long)b << 20) + ((long)f << 10);

  if (tid < 256) {
    wpreS[tid] = pre[tid] * 1.44269504f;   // fold log2(e) into pre-mix
    wpostS[tid] = post[tid];
  }

  // staging role: nh = n-half (0/1), p = t-pair index within chunk
  int nh = tid >> 8, p = tid & 255;
  const unsigned short* sAddr = scb + ((long)(nh * 8) << 20) + 2 * p;
  short* rowE = &Sb[(2 * p) * 20 + nh * 8];
  short* rowO = &Sb[(2 * p + 1) * 20 + nh * 8];

  int tb = w * 64 + r;                  // wave-local col base within chunk

  unsigned epk[8][2];
  f32x4 zacc = (f32x4){0.f, 0.f, 0.f, 0.f};

  // ---- load chunk 0 + prefetch ALL mask words (latency overlapped)
  unsigned ld[8];
  #pragma unroll
  for (int i = 0; i < 8; ++i)
    ld[i] = *(const unsigned*)(sAddr + ((long)i << 20));
  float madds[8];
  #pragma unroll
  for (int c2 = 0; c2 < 2; ++c2)
    #pragma unroll
    for (int it = 0; it < 4; ++it) {
      int mm = mk[c2 * 512 + tb + it * 16];
      madds[c2 * 4 + it] = (1.0f - (float)mm) * -14426.9504f;  // -1e4*log2e
    }
  __syncthreads();                      // wpreS/wpostS ready

  // A1 = wpre^T * log2e (k zero-padded 16->32)
  short8 af1;
  #pragma unroll
  for (int i = 0; i < 8; ++i) {
    int n = ((g & 1) << 3) + i;
    bf16 hv = __float2bfloat16(wpreS[n * 16 + r]);
    af1[i] = (g < 2) ? *(short*)&hv : (short)0;
  }

  wrows7(rowE, rowO, ld);               // stage chunk 0
  __syncthreads();

  // prefetch chunk 1 (latency hides under chunk-0 compute)
  #pragma unroll
  for (int i = 0; i < 8; ++i)
    ld[i] = *(const unsigned*)(sAddr + ((long)i << 20) + 512);

  compute_chunk9<0>(Sb, madds, tb, g, af1, zacc, epk);
  __syncthreads();                      // chunk-0 reads done
  wrows7(rowE, rowO, ld);               // stage chunk 1
  __syncthreads();
  compute_chunk9<1>(Sb, madds, tb, g, af1, zacc, epk);

  // denominator: butterfly over the 16 cols, one f32x4 per wave
  #pragma unroll
  for (int m2 = 1; m2 < 16; m2 <<= 1) {
    #pragma unroll
    for (int j = 0; j < 4; ++j) zacc[j] += __shfl_xor(zacc[j], m2, 64);
  }
  if (r == 0) *(f32x4*)&zred[w][g * 4] = zacc;
  __syncthreads();
  if (tid < 64) {                       // one-wave parallel zinv
    int l2 = tid & 15, h = tid >> 4;
    float zsum = zred[h][l2] + zred[h + 4][l2];
    zsum += __shfl_xor(zsum, 16, 64);
    zsum += __shfl_xor(zsum, 32, 64);
    if (tid < 16) zinvs[tid] = 1.0f / zsum;
  }
  __syncthreads();

  // A2 = wpost^T with zinv folded in
  short8 af2;
  #pragma unroll
  for (int i = 0; i < 8; ++i) {
    int n = ((g & 1) << 3) + i;
    bf16 hv = __float2bfloat16(wpostS[n * 16 + r] * zinvs[n]);
    af2[i] = (g < 2) ? *(short*)&hv : (short)0;
  }

  pass2_chunk7<0>(Sb, scb, tb, g, af2, epk, rowE, rowO, nh, p);
  __syncthreads();
  pass2_chunk7<1>(Sb, scb, tb, g, af2, epk, rowE, rowO, nh, p);
}

// ---------------------------------------------------------------------------
// B=4, S=1024, D=1024, N=16, H=64. fp32 I/O, bf16 internal.
// ws (bf16 elems, M1=1<<20): big path 85M = 170 MB (Sc 64M overlapping the
// dead phase-1 staging), small path 37M = 74 MB (per-batch Sc 16M).
// ---------------------------------------------------------------------------
extern "C" void kernel_launch(void* const* d_in, const int* in_sizes, int n_in,
                              void* d_out, int out_size, void* d_ws, size_t ws_size,
                              hipStream_t stream) {
  const float* from = (const float*)d_in[0];
  const float* to   = (const float*)d_in[1];
  const int*  mask  = (const int*)d_in[2];
  const float* wq = (const float*)d_in[3];
  const float* bq = (const float*)d_in[4];
  const float* wk = (const float*)d_in[5];
  const float* bk = (const float*)d_in[6];
  const float* wv = (const float*)d_in[7];
  const float* bv = (const float*)d_in[8];
  const float* pre  = (const float*)d_in[9];
  const float* post = (const float*)d_in[10];
  const float* wo = (const float*)d_in[11];
  const float* bo = (const float*)d_in[12];
  float* out = (float*)d_out;

  bf16* W = (bf16*)d_ws;
  const long M1 = 1048576;
  bool big = ws_size >= (size_t)(85 * M1) * 2;

  bf16 *Sc, *fromB, *toB, *wqT, *wkT, *wvT, *woT, *Q, *Kp, *Vt, *ctx;
  if (big) {
    Sc = W;                 fromB = W;            toB = W + 4 * M1;
    wqT = W + 8 * M1;       wkT = W + 9 * M1;     wvT = W + 10 * M1;
    woT = W + 64 * M1;      Q = W + 65 * M1;      Kp = W + 69 * M1;
    Vt = W + 77 * M1;       ctx = W + 81 * M1;
  } else {
    Sc = W;                 fromB = W;            toB = W + 4 * M1;
    wqT = W + 8 * M1;       wkT = W + 9 * M1;     wvT = W + 10 * M1;
    woT = W + 16 * M1;      Q = W + 17 * M1;      Kp = W + 21 * M1;
    Vt = W + 29 * M1;       ctx = W + 33 * M1;
  }

  dim3 blk(256);

  // 1) merged converts + weight transposes (single dispatch)
  CvtW cw;
  cw.cf[0] = from; cw.cf[1] = to;
  cw.co[0] = fromB; cw.co[1] = toB;
  cw.ws[0] = wq; cw.ws[1] = wk; cw.ws[2] = wv; cw.ws[3] = wo;
  cw.wd[0] = wqT; cw.wd[1] = wkT; cw.wd[2] = wvT; cw.wd[3] = woT;
  cvtwt<<<dim3(2048, 1, 6), blk, 0, stream>>>(cw);

  // 2) QKV projections (1 z-batched dispatch, R9 config); z=2 writes Vt
  QKVArgs qa;
  qa.A[0] = fromB; qa.A[1] = toB; qa.A[2] = toB;
  qa.Bw[0] = wqT;  qa.Bw[1] = wkT; qa.Bw[2] = wvT;
  qa.C[0] = Q;     qa.C[1] = Kp;  qa.C[2] = Vt;
  qa.bias[0] = bq; qa.bias[1] = bk; qa.bias[2] = bv;
  gemm_qkv<<<dim3(32, 16, 3), blk, 0, stream>>>(qa);

  if (big) {
    // 3) scores (direct K=64): z=(b,n): Sc[b,n] = 0.125*Q[b,:,n,:]@K[b,:,n,:]^T
    gemm_k64<<<dim3(8, 8, 64), blk, 0, stream>>>(
        Q, M1, 64, 1024, Kp, M1, 64, 1024, Sc, 16 * M1, M1, 1024, 16, 0.125f);
    // 4) talking-heads softmax (v9 — 1 row/block, L3-absorbed)
    mixsoftmax9<<<dim3(1024, 4), dim3(512), 0, stream>>>(Sc, 16 * M1, pre, post, mask);
    // 5) PV: z=(b,l): ctx[b,:,l,:] = Sc[b,l]@Vt[b,l]^T
    gemm_lds64<<<dim3(8, 1, 64), blk, 0, stream>>>(
        Sc, 16 * M1, M1, 1024, Vt, M1, 65536, 1024, ctx, M1, 64, 1024, nullptr,
        1024, 16, 1.0f, 0);
  } else {
    for (int b = 0; b < 4; ++b) {
      gemm_k64<<<dim3(8, 8, 16), blk, 0, stream>>>(
          Q + b * M1, 0, 64, 1024, Kp + b * M1, 0, 64, 1024,
          Sc, 0, M1, 1024, 16, 0.125f);
      mixsoftmax9<<<dim3(1024, 1), dim3(512), 0, stream>>>(Sc, 0, pre, post, mask + b * M1);
      gemm_lds64<<<dim3(8, 1, 16), blk, 0, stream>>>(
          Sc, 0, M1, 1024, Vt + b * M1, 0, 65536, 1024,
          ctx + b * M1, 0, 64, 1024, nullptr, 1024, 16, 1.0f, 0);
    }
  }

  // 6) out = ctx [4096,1024] @ woT^T + bo -> d_out (fp32), 128x64 tiles
  gemm_lds64<<<dim3(32, 16, 1), blk, 0, stream>>>(
      ctx, 0, 0, 1024, woT, 0, 0, 1024, out, 0, 0, 1024, bo, 1024, 1, 1.0f, 1);
}